// Round 3
// baseline (110.767 us; speedup 1.0000x reference)
//
#include <hip/hip_runtime.h>
#include <hip/hip_bf16.h>
#include <hip/hip_fp16.h>

#define PP 9216   // 96*96 pixels per batch
#define OO 384    // qkv channels

typedef _Float16 f16x8 __attribute__((ext_vector_type(8)));
typedef _Float16 h2    __attribute__((ext_vector_type(2)));
typedef float    f32x4 __attribute__((ext_vector_type(4)));

#if defined(__has_builtin)
# if __has_builtin(__builtin_amdgcn_fdot2)
#  define HAS_FDOT2 1
# endif
#endif

__device__ __forceinline__ float dot2acc(h2 a, h2 b, float c) {
#ifdef HAS_FDOT2
    return __builtin_amdgcn_fdot2(a, b, c, false);
#else
    return c + (float)a[0] * (float)b[0] + (float)a[1] * (float)b[1];
#endif
}

// ---------------------------------------------------------------------------
// prep: (y<4) transpose x[b][c][p] f32 -> xT[b][p][c] f16 in 32x32 tiles;
//       (y==4,z==0) convert qkv weights to f16 (wq|wk|wv concat rows).
// ---------------------------------------------------------------------------
__global__ __launch_bounds__(256) void prep(
    const float* __restrict__ x, const float* __restrict__ wq,
    const float* __restrict__ wk, const float* __restrict__ wv,
    _Float16* __restrict__ xT, _Float16* __restrict__ wqkv)
{
    const int t = threadIdx.x;
    if (blockIdx.y == 4) {
        if (blockIdx.z) return;
        int idx = blockIdx.x * 256 + t;
        if (idx < 49152) {
            int o = idx >> 7;
            const float* src = (o < 128) ? wq : ((o < 256) ? wk : wv);
            wqkv[idx] = (_Float16)src[(o & 127) * 128 + (idx & 127)];
        }
        return;
    }
    __shared__ float sT[32][33];
    const int p0 = blockIdx.x * 32;
    const int c0 = blockIdx.y * 32;
    const int b  = blockIdx.z;
    const int row = t >> 3, col = t & 7;

    const float* xb = x + (size_t)b * 128 * PP;
    float4 v = *(const float4*)(xb + (size_t)(c0 + row) * PP + p0 + col * 4);
    sT[col * 4 + 0][row] = v.x;
    sT[col * 4 + 1][row] = v.y;
    sT[col * 4 + 2][row] = v.z;
    sT[col * 4 + 3][row] = v.w;
    __syncthreads();

    _Float16 h[4];
    #pragma unroll
    for (int j = 0; j < 4; j++) h[j] = (_Float16)sT[row][col * 4 + j];
    *(ushort4*)(xT + (size_t)b * PP * 128 + (size_t)(p0 + row) * 128 + c0 + col * 4) =
        *(ushort4*)h;
}

// ---------------------------------------------------------------------------
// QKV GEMM: qkv[b][p][o] = sum_c xT[b][p][c] * wqkv[o][c], f16 MFMA, no LDS
// staging; LDS epilogue for coalesced 16B stores (192B runs per pixel row).
// Block: 64px x 192o. Wave: 32px x 96o.
// ---------------------------------------------------------------------------
__global__ __launch_bounds__(256) void qkv_gemm(
    const _Float16* __restrict__ xT, const _Float16* __restrict__ wqkv,
    _Float16* __restrict__ qkv)
{
    __shared__ _Float16 sEpi[4][32][104];   // per-wave 32px x 96o strip (pad 104)

    const int b = blockIdx.z;
    const int p0 = blockIdx.x * 64;
    const int nbase = blockIdx.y * 192;
    const int t = threadIdx.x;
    const int w = t >> 6, lane = t & 63;
    const int lm = lane & 15, quad = lane >> 4;
    const int ms0 = (w & 1) * 32;
    const int nw = (w >> 1) * 96;

    const _Float16* xb = xT + (size_t)b * PP * 128;
    _Float16* qb = qkv + (size_t)b * PP * OO;

    f16x8 A[2][4];
    #pragma unroll
    for (int ms = 0; ms < 2; ms++)
        #pragma unroll
        for (int kc = 0; kc < 4; kc++)
            A[ms][kc] = *(const f16x8*)(xb + (size_t)(p0 + ms0 + ms * 16 + lm) * 128
                                        + kc * 32 + quad * 8);

    for (int nt = 0; nt < 6; nt++) {
        const int n0 = nbase + nw + nt * 16;
        f16x8 Bf[4];
        #pragma unroll
        for (int kc = 0; kc < 4; kc++)
            Bf[kc] = *(const f16x8*)(wqkv + (size_t)(n0 + lm) * 128 + kc * 32 + quad * 8);
        f32x4 acc[2];
        #pragma unroll
        for (int ms = 0; ms < 2; ms++) {
            acc[ms] = (f32x4){0.f, 0.f, 0.f, 0.f};
            #pragma unroll
            for (int kc = 0; kc < 4; kc++)
                acc[ms] = __builtin_amdgcn_mfma_f32_16x16x32_f16(A[ms][kc], Bf[kc], acc[ms], 0, 0, 0);
        }
        #pragma unroll
        for (int ms = 0; ms < 2; ms++)
            #pragma unroll
            for (int r = 0; r < 4; r++)
                sEpi[w][ms * 16 + quad * 4 + r][nt * 16 + lm] = (_Float16)acc[ms][r];
    }

    // per-wave epilogue: 32 rows x 96 halfs (192B contiguous per row)
    #pragma unroll
    for (int it = 0; it < 6; it++) {
        int idx = it * 64 + lane;      // 0..383
        int row = idx / 12;            // 0..31
        int ch  = idx % 12;            // 16B chunk within row
        uint4 v = *(const uint4*)&sEpi[w][row][ch * 8];
        *(uint4*)(qb + (size_t)(p0 + ms0 + row) * OO + nbase + nw + ch * 8) = v;
    }
}

// ---------------------------------------------------------------------------
// Fused windowed attention + output projection.
// Block = 8-wide x 4-tall pixel tile, one batch. Heads looped in-block.
// qkv[b][p][384] f16 (q:0-127, k:128-255, v:256-383; each h*32+d).
// ao tile accumulated in LDS f16, then proj via MFMA -> out[b][c][p] f32.
// ---------------------------------------------------------------------------
__global__ __launch_bounds__(256) void attn_proj(
    const _Float16* __restrict__ qkv, const float* __restrict__ wp,
    float* __restrict__ out)
{
    __shared__ _Float16 sK[96 * 40];    // halo 8 rows x 12 cols, 32 d (pad 40)
    __shared__ _Float16 sV[96 * 40];
    __shared__ float    sS[32 * 29];    // scores, stride 29 (bank-friendly)
    __shared__ _Float16 sAo[32 * 136];  // [px][128 o], stride 136 (16B-aligned)

    const int t  = threadIdx.x;
    const int x0 = blockIdx.x * 8;
    const int y0 = blockIdx.y * 4;
    const int b  = blockIdx.z;
    const _Float16* base = qkv + (size_t)b * PP * OO;

    const int px = t & 31, w8 = t >> 5;       // 8 groups of 32
    const int ly = px >> 3, lx = px & 7;
    const int gp0 = (y0 + ly) * 96 + x0 + lx;
    const float scale = 0.17677669529663689f; // 1/sqrt(32)

    for (int h = 0; h < 4; h++) {
        // stage K,V halo for head h: 96 pos x 32 halfs, contiguous 64B rows
        if (t < 192) {
            const int arr = (t >= 96) ? 1 : 0;
            const int pos = t - 96 * arr;
            const int gy = y0 - 2 + pos / 12;
            const int gx = x0 - 2 + pos % 12;
            _Float16* dst = (arr ? sV : sK) + pos * 40;
            if ((unsigned)gy < 96u && (unsigned)gx < 96u) {
                const _Float16* src = base + (size_t)(gy * 96 + gx) * OO + 128 + arr * 128 + h * 32;
                #pragma unroll
                for (int j = 0; j < 4; j++)
                    *(uint4*)(dst + j * 8) = *(const uint4*)(src + j * 8);
            } else {
                uint4 z = {0u, 0u, 0u, 0u};
                #pragma unroll
                for (int j = 0; j < 4; j++) *(uint4*)(dst + j * 8) = z;
            }
        }
        // Q into registers
        h2 qreg[16];
        {
            const _Float16* qs = base + (size_t)gp0 * OO + h * 32;
            #pragma unroll
            for (int j = 0; j < 4; j++)
                *(uint4*)(&qreg[j * 4]) = *(const uint4*)(qs + j * 8);
        }
        __syncthreads();

        // scores: group w8 handles pos = w8, w8+8, ...
        for (int pos = w8; pos < 25; pos += 8) {
            const int hp = (ly + pos / 5) * 12 + lx + pos % 5;
            const _Float16* kr = sK + hp * 40;
            h2 kreg[16];
            #pragma unroll
            for (int j = 0; j < 4; j++)
                *(uint4*)(&kreg[j * 4]) = *(const uint4*)(kr + j * 8);
            float s0 = 0.f, s1 = 0.f;
            #pragma unroll
            for (int j = 0; j < 8; j++) {
                s0 = dot2acc(qreg[2 * j], kreg[2 * j], s0);
                s1 = dot2acc(qreg[2 * j + 1], kreg[2 * j + 1], s1);
            }
            sS[px * 29 + pos] = (s0 + s1) * scale;
        }
        __syncthreads();

        // softmax over 25 positions (one thread per pixel)
        if (t < 32) {
            float* row = sS + t * 29;
            float m = row[0];
            #pragma unroll
            for (int p = 1; p < 25; p++) m = fmaxf(m, row[p]);
            float sum = 0.f;
            float e[25];
            #pragma unroll
            for (int p = 0; p < 25; p++) { e[p] = __expf(row[p] - m); sum += e[p]; }
            const float inv = 1.f / sum;
            #pragma unroll
            for (int p = 0; p < 25; p++) row[p] = e[p] * inv;
        }
        __syncthreads();

        // PV: group w8 handles d in [w8*4, w8*4+4)
        float at[25];
        #pragma unroll
        for (int p = 0; p < 25; p++) at[p] = sS[px * 29 + p];

        float f[4] = {0.f, 0.f, 0.f, 0.f};
        for (int p = 0; p < 25; p++) {
            const int hp = (ly + p / 5) * 12 + lx + p % 5;
            h2 vreg[2];
            *(uint2*)vreg = *(const uint2*)(sV + hp * 40 + w8 * 4);
            #pragma unroll
            for (int j = 0; j < 2; j++) {
                f[2 * j]     += at[p] * (float)vreg[j][0];
                f[2 * j + 1] += at[p] * (float)vreg[j][1];
            }
        }
        _Float16 ho[4];
        #pragma unroll
        for (int j = 0; j < 4; j++) ho[j] = (_Float16)f[j];
        *(ushort4*)(sAo + px * 136 + h * 32 + w8 * 4) = *(ushort4*)ho;
        __syncthreads();   // also protects sK/sV re-stage next head
    }

    // ---- projection: out[c][px] = sum_o wp[c][o] * ao[px][o] ----
    const int lane = t & 63, w4 = t >> 6;
    const int lm = lane & 15, quad = lane >> 4;

    f16x8 Aw[2][4];   // wproj rows c = w4*32 + mt*16 + lm, k-chunks of 32 o
    #pragma unroll
    for (int mt = 0; mt < 2; mt++)
        #pragma unroll
        for (int kc = 0; kc < 4; kc++) {
            const float* ws_ = wp + (size_t)(w4 * 32 + mt * 16 + lm) * 128 + kc * 32 + quad * 8;
            float4 a0 = *(const float4*)ws_;
            float4 a1 = *(const float4*)(ws_ + 4);
            Aw[mt][kc] = (f16x8){(_Float16)a0.x, (_Float16)a0.y, (_Float16)a0.z, (_Float16)a0.w,
                                 (_Float16)a1.x, (_Float16)a1.y, (_Float16)a1.z, (_Float16)a1.w};
        }

    f32x4 acc[2][2];
    #pragma unroll
    for (int mt = 0; mt < 2; mt++)
        #pragma unroll
        for (int nt = 0; nt < 2; nt++)
            acc[mt][nt] = (f32x4){0.f, 0.f, 0.f, 0.f};

    #pragma unroll
    for (int nt = 0; nt < 2; nt++) {
        f16x8 Bf[4];
        #pragma unroll
        for (int kc = 0; kc < 4; kc++)
            Bf[kc] = *(const f16x8*)(sAo + (nt * 16 + lm) * 136 + kc * 32 + quad * 8);
        #pragma unroll
        for (int mt = 0; mt < 2; mt++)
            #pragma unroll
            for (int kc = 0; kc < 4; kc++)
                acc[mt][nt] = __builtin_amdgcn_mfma_f32_16x16x32_f16(Aw[mt][kc], Bf[kc], acc[mt][nt], 0, 0, 0);
    }

    float* ob = out + (size_t)b * 128 * PP;
    #pragma unroll
    for (int mt = 0; mt < 2; mt++)
        #pragma unroll
        for (int nt = 0; nt < 2; nt++) {
            const int pxl = nt * 16 + lm;
            const int gpl = (y0 + (pxl >> 3)) * 96 + x0 + (pxl & 7);
            #pragma unroll
            for (int r = 0; r < 4; r++) {
                const int c = w4 * 32 + mt * 16 + quad * 4 + r;
                ob[(size_t)c * PP + gpl] = acc[mt][nt][r];
            }
        }
}

extern "C" void kernel_launch(void* const* d_in, const int* in_sizes, int n_in,
                              void* d_out, int out_size, void* d_ws, size_t ws_size,
                              hipStream_t stream)
{
    const float* x  = (const float*)d_in[0];
    const float* wq = (const float*)d_in[1];
    const float* wk = (const float*)d_in[2];
    const float* wv = (const float*)d_in[3];
    const float* wp = (const float*)d_in[4];
    float* out = (float*)d_out;

    _Float16* ws    = (_Float16*)d_ws;
    _Float16* xT    = ws;                       // 2*9216*128
    _Float16* wqkv  = xT + 2359296;             // 384*128
    _Float16* qkvh  = wqkv + 49152;             // 2*9216*384

    prep<<<dim3(288, 5, 2), 256, 0, stream>>>(x, wq, wk, wv, xT, wqkv);
    qkv_gemm<<<dim3(144, 2, 2), 256, 0, stream>>>(xT, wqkv, qkvh);
    attn_proj<<<dim3(12, 24, 2), 256, 0, stream>>>(qkvh, wp, out);
}